// Round 17
// baseline (62.091 us; speedup 1.0000x reference)
//
#include <hip/hip_runtime.h>
#include <hip/hip_bf16.h>

#define C_DIM 256
#define N_SP  4096
#define HEADS 8
#define HD    32
#define GSIZE (HD * N_SP)

typedef __attribute__((ext_vector_type(8))) short bf16x8;
typedef __attribute__((ext_vector_type(4))) float f32x4;
typedef __attribute__((ext_vector_type(4))) unsigned u32x4;

__device__ inline unsigned short f2bf(float f) {
  unsigned int u = __builtin_bit_cast(unsigned int, f);
  u = (u + 0x7fffu + ((u >> 16) & 1u)) >> 16;   // RNE
  return (unsigned short)u;
}
__device__ inline float bf2f(unsigned short b) {
  return __builtin_bit_cast(float, (unsigned)b << 16);
}

__device__ inline unsigned cvtpk_bf16(float lo, float hi) {
  unsigned r;
  asm("v_cvt_pk_bf16_f32 %0, %1, %2" : "=v"(r) : "v"(lo), "v"(hi));
  return r;
}
__device__ inline void pl32swap(unsigned &x, unsigned &y) {
  asm("v_permlane32_swap_b32 %0, %1" : "+v"(x), "+v"(y));
}
__device__ inline void pl16swap(unsigned &x, unsigned &y) {
  asm("v_permlane16_swap_b32 %0, %1" : "+v"(x), "+v"(y));
}
__device__ inline void gload_lds16(const void* g, void* l) {
  __builtin_amdgcn_global_load_lds(
      (const __attribute__((address_space(1))) void*)g,
      (__attribute__((address_space(3))) void*)l, 16, 0, 0);
}

// ---- fused: GN partial stats (blocks 0-63, 8 sub/group) + w-cvt (64-127) ---
__global__ __launch_bounds__(1024) void stats_cvt(const float* __restrict__ x,
                                                  float* __restrict__ pstats,
                                                  const float* __restrict__ wq,
                                                  const float* __restrict__ wk,
                                                  const float* __restrict__ wv,
                                                  const float* __restrict__ wo,
                                                  unsigned short* __restrict__ dst) {
  int t = threadIdx.x;
  if (blockIdx.x < 64) {
    int g = blockIdx.x >> 3, sub = blockIdx.x & 7;
    const float4* xg = reinterpret_cast<const float4*>(
        x + (size_t)g * GSIZE + (size_t)sub * (GSIZE / 8));
    float s1 = 0.f, s2 = 0.f;
#pragma unroll
    for (int i = 0; i < 4; ++i) {
      float4 v = xg[t + i * 1024];
      s1 += v.x + v.y + v.z + v.w;
      s2 += v.x * v.x + v.y * v.y + v.z * v.z + v.w * v.w;
    }
    for (int off = 1; off < 64; off <<= 1) {
      s1 += __shfl_xor(s1, off);
      s2 += __shfl_xor(s2, off);
    }
    __shared__ float red[16][2];
    int wid = t >> 6;
    if ((t & 63) == 0) { red[wid][0] = s1; red[wid][1] = s2; }
    __syncthreads();
    if (t < 16) {
      s1 = red[t][0]; s2 = red[t][1];
      for (int off = 1; off < 16; off <<= 1) {
        s1 += __shfl_xor(s1, off);
        s2 += __shfl_xor(s2, off);
      }
      if (t == 0) {
        pstats[(g * 8 + sub) * 2] = s1;
        pstats[(g * 8 + sub) * 2 + 1] = s2;
      }
    }
  } else {
    int i = (blockIdx.x - 64) * 1024 + t;   // 0..65535, quad index
    int mat = i >> 14;
    int idx = i & 16383;
    const float* src = (mat == 0) ? wq : (mat == 1) ? wk : (mat == 2) ? wv : wo;
    float4 v = reinterpret_cast<const float4*>(src)[idx];
    ushort4 o;
    o.x = f2bf(v.x); o.y = f2bf(v.y); o.z = f2bf(v.z); o.w = f2bf(v.w);
    reinterpret_cast<ushort4*>(dst + (size_t)mat * 65536)[idx] = o;
  }
}

// ---- fused GN-apply + QKV projection -----
// 512 blocks x 256 thr: block = 16 p-rows (bid>>1) x 128 o-half (bid&1).
__global__ __launch_bounds__(256) void gn_qkv(const float* __restrict__ x,
                                              const float* __restrict__ pstats,
                                              const float* __restrict__ gsc,
                                              const float* __restrict__ gbi,
                                              const unsigned short* __restrict__ wbf,
                                              const float* __restrict__ bq,
                                              const float* __restrict__ bk,
                                              const float* __restrict__ bv,
                                              unsigned short* __restrict__ qt,
                                              unsigned short* __restrict__ kt,
                                              unsigned short* __restrict__ vv) {
  __shared__ unsigned short xt[16][264];   // 8448 B, row pitch 528 B
  int t = threadIdx.x;
  int p0 = (blockIdx.x >> 1) * 16;
  int oh = (blockIdx.x & 1) * 128;

  // ---- phase 1 ----
  {
    int pl = t & 15;          // p within slab
    int cb = t >> 4;          // 16-channel chunk 0..15
    int c0 = cb * 16;
    int g = c0 >> 5;
    float s1 = 0.f, s2 = 0.f;
#pragma unroll
    for (int s = 0; s < 8; ++s) {
      s1 += pstats[(g * 8 + s) * 2];
      s2 += pstats[(g * 8 + s) * 2 + 1];
    }
    float mu = s1 / (float)GSIZE;
    float rs = rsqrtf(s2 / (float)GSIZE - mu * mu + 1e-5f);
#pragma unroll
    for (int j = 0; j < 16; ++j) {
      float sc = gsc[c0 + j] * rs;
      float bi = gbi[c0 + j] - mu * sc;
      xt[pl][c0 + j] = f2bf(x[(size_t)(c0 + j) * N_SP + p0 + pl] * sc + bi);
    }
  }
  __syncthreads();

  // ---- phase 2 ----
  int w = t >> 6, lc = t & 15, lg = (t & 63) >> 4;
  int ow = oh + w * 32;
  f32x4 aq[2], ak[2], av[2];
#pragma unroll
  for (int i = 0; i < 2; ++i) {
    aq[i] = (f32x4){0.f, 0.f, 0.f, 0.f};
    ak[i] = (f32x4){0.f, 0.f, 0.f, 0.f};
    av[i] = (f32x4){0.f, 0.f, 0.f, 0.f};
  }
#pragma unroll
  for (int it = 0; it < 8; ++it) {
    bf16x8 a = *reinterpret_cast<const bf16x8*>(&xt[lc][it * 32 + 8 * lg]);
#pragma unroll
    for (int ni = 0; ni < 2; ++ni) {
      size_t rowoff = (size_t)(ow + 16 * ni + lc) * C_DIM + it * 32 + 8 * lg;
      bf16x8 bQ = *reinterpret_cast<const bf16x8*>(wbf + rowoff);
      bf16x8 bK = *reinterpret_cast<const bf16x8*>(wbf + 65536 + rowoff);
      bf16x8 bV = *reinterpret_cast<const bf16x8*>(wbf + 131072 + rowoff);
      aq[ni] = __builtin_amdgcn_mfma_f32_16x16x32_bf16(a, bQ, aq[ni], 0, 0, 0);
      ak[ni] = __builtin_amdgcn_mfma_f32_16x16x32_bf16(a, bK, ak[ni], 0, 0, 0);
      av[ni] = __builtin_amdgcn_mfma_f32_16x16x32_bf16(bV, a, av[ni], 0, 0, 0);
    }
  }
#pragma unroll
  for (int ni = 0; ni < 2; ++ni) {
    int o = ow + 16 * ni + lc;
    float bqv = bq[o], bkv = bk[o];
#pragma unroll
    for (int r = 0; r < 4; ++r) {
      qt[(size_t)(p0 + 4 * lg + r) * C_DIM + o] =
          f2bf((aq[ni][r] + bqv) * 0.25503344494963116f);  // hd^-0.5 * log2(e)
      kt[(size_t)(p0 + 4 * lg + r) * C_DIM + o] = f2bf(ak[ni][r] + bkv);
    }
  }
#pragma unroll
  for (int mi = 0; mi < 2; ++mi)
#pragma unroll
    for (int r = 0; r < 4; ++r) {
      int o = ow + 16 * mi + 4 * lg + r;
      vv[(size_t)o * N_SP + p0 + lc] = f2bf(av[mi][r] + bv[o]);
    }
}

// ------------- flash attention (no-max, wave-private ksplit, 0-barrier) ----
// 512 blocks linear; XCD-pin: h = bid&7 (round-robin dispatch puts all blocks
// of head h on XCD h -> its K/V (512 KB) + Q slice L2-resident per-XCD).
// Block = 4 waves sharing the SAME 64 queries; wave w owns keys
// [w*1024, +1024) staged into its PRIVATE 16 KB LDS region (double-buffered
// 8 KB halves) via global_load_lds, counted vmcnt(8), no main-loop barrier.
// End: one barrier, cross-wave O/l reduction, write aot directly.

#define STAGE_W(BUF, IT)                                                      \
  {                                                                           \
    _Pragma("unroll")                                                         \
    for (int i = 0; i < 4; ++i)                                               \
      gload_lds16(ksrc + (size_t)(IT) * 32768 + i * 8192,                     \
                  region + (BUF) * 8192 + i * 1024);                          \
    _Pragma("unroll")                                                         \
    for (int j = 0; j < 4; ++j)                                               \
      gload_lds16(vsrc + (size_t)(IT) * 128 + j * 65536,                      \
                  region + (BUF) * 8192 + 4096 + j * 1024);                   \
  }

#define CHAIN(KF, VF)                                                         \
  {                                                                           \
    f32x4 s[4];                                                               \
    _Pragma("unroll")                                                         \
    for (int ni = 0; ni < 4; ++ni) {                                          \
      f32x4 z = (f32x4){0.f, 0.f, 0.f, 0.f};                                  \
      s[ni] = __builtin_amdgcn_mfma_f32_16x16x32_bf16(KF[ni], qf[qi], z, 0, 0, 0); \
    }                                                                         \
    unsigned wd[4][2];                                                        \
    _Pragma("unroll")                                                         \
    for (int ni = 0; ni < 4; ++ni) {                                          \
      float p0e = __builtin_amdgcn_exp2f(s[ni][0]);                           \
      float p1e = __builtin_amdgcn_exp2f(s[ni][1]);                           \
      float p2e = __builtin_amdgcn_exp2f(s[ni][2]);                           \
      float p3e = __builtin_amdgcn_exp2f(s[ni][3]);                           \
      wd[ni][0] = cvtpk_bf16(p0e, p1e);                                       \
      wd[ni][1] = cvtpk_bf16(p2e, p3e);                                       \
    }                                                                         \
    bf16x8 ap[2];                                                             \
    _Pragma("unroll")                                                         \
    for (int kk = 0; kk < 2; ++kk) {                                          \
      unsigned a0 = wd[2 * kk][0], b0 = wd[2 * kk + 1][0];                    \
      unsigned a1 = wd[2 * kk][1], b1 = wd[2 * kk + 1][1];                    \
      pl32swap(a0, b0); pl16swap(a0, b0);                                     \
      pl32swap(a1, b1); pl16swap(a1, b1);                                     \
      u32x4 pk = {a0, a1, b0, b1};                                            \
      ap[kk] = __builtin_bit_cast(bf16x8, pk);                                \
    }                                                                         \
    lacc[qi] = __builtin_amdgcn_mfma_f32_16x16x32_bf16(ap[0], ones, lacc[qi], 0, 0, 0); \
    oacc[qi][0] = __builtin_amdgcn_mfma_f32_16x16x32_bf16(ap[0], VF[0][0], oacc[qi][0], 0, 0, 0); \
    oacc[qi][1] = __builtin_amdgcn_mfma_f32_16x16x32_bf16(ap[0], VF[0][1], oacc[qi][1], 0, 0, 0); \
    lacc[qi] = __builtin_amdgcn_mfma_f32_16x16x32_bf16(ap[1], ones, lacc[qi], 0, 0, 0); \
    oacc[qi][0] = __builtin_amdgcn_mfma_f32_16x16x32_bf16(ap[1], VF[1][0], oacc[qi][0], 0, 0, 0); \
    oacc[qi][1] = __builtin_amdgcn_mfma_f32_16x16x32_bf16(ap[1], VF[1][1], oacc[qi][1], 0, 0, 0); \
  }

#define COMPUTE_W(BUF)                                                        \
  {                                                                           \
    bf16x8 kf[4], vf[2][2];                                                   \
    _Pragma("unroll")                                                         \
    for (int ni = 0; ni < 4; ++ni)                                            \
      kf[ni] = *reinterpret_cast<const bf16x8*>(region + (BUF) * 8192 + ni * 1024 + krd); \
    _Pragma("unroll")                                                         \
    for (int dd = 0; dd < 2; ++dd) {                                          \
      vf[0][dd] = *reinterpret_cast<const bf16x8*>(region + (BUF) * 8192 + 4096 + dd * 2048 + vrd0); \
      vf[1][dd] = *reinterpret_cast<const bf16x8*>(region + (BUF) * 8192 + 4096 + dd * 2048 + vrd1); \
    }                                                                         \
    _Pragma("unroll")                                                         \
    for (int qi = 0; qi < 4; ++qi) { CHAIN(kf, vf) }                          \
  }

#define WAIT_VM(N)                                                            \
  {                                                                           \
    asm volatile("s_waitcnt vmcnt(" #N ")" ::: "memory");                     \
    __builtin_amdgcn_sched_barrier(0);                                        \
  }
#define WAIT_LGKM                                                             \
  {                                                                           \
    asm volatile("s_waitcnt lgkmcnt(0)" ::: "memory");                        \
    __builtin_amdgcn_sched_barrier(0);                                        \
  }

__global__ __launch_bounds__(256, 2) void attn_part(const unsigned short* __restrict__ qt,
                                                    const unsigned short* __restrict__ kt,
                                                    const unsigned short* __restrict__ v,
                                                    unsigned short* __restrict__ aot) {
  __shared__ __align__(1024) char smem[65536];
  int t = threadIdx.x;
  int w = t >> 6, lane = t & 63, lc = t & 15, lg = (t & 63) >> 4;
  int bid = blockIdx.x;
  int h = bid & 7;             // XCD-pin: one head per XCD
  int nq0 = (bid >> 3) * 64;
  int hc = h * HD;
  char* region = smem + w * 16384;

  // per-wave staging sources (inverse-swizzled), quarter = keys [w*1024, +1024)
  int krow = lane >> 2;
  int kc16 = (lane & 3) ^ (krow & 3);
  const char* ksrc = (const char*)(kt + (size_t)(w * 1024 + krow) * C_DIM + hc + 8 * kc16);
  int vrow = lane >> 3;
  int vn16 = (lane & 7) ^ (vrow & 7);
  const char* vsrc = (const char*)(v + (size_t)(hc + vrow) * N_SP + w * 1024 + 8 * vn16);

  // LDS read per-lane byte offsets (swizzled), as R8
  int krd = lc * 64 + 16 * (lg ^ (lc & 3));
  int vrd0 = lc * 128 + 16 * ((lg + 0) ^ (lc & 7));
  int vrd1 = lc * 128 + 16 * ((lg + 4) ^ (lc & 7));

  bf16x8 qf[4];
#pragma unroll
  for (int qi = 0; qi < 4; ++qi)
    qf[qi] = *reinterpret_cast<const bf16x8*>(
        qt + (size_t)(nq0 + 16 * qi + lc) * C_DIM + hc + 8 * lg);

  f32x4 oacc[4][2], lacc[4];
#pragma unroll
  for (int qi = 0; qi < 4; ++qi) {
    lacc[qi] = (f32x4){0.f, 0.f, 0.f, 0.f};
#pragma unroll
    for (int dd = 0; dd < 2; ++dd) oacc[qi][dd] = (f32x4){0.f, 0.f, 0.f, 0.f};
  }
  const bf16x8 ones = {0x3F80, 0x3F80, 0x3F80, 0x3F80, 0x3F80, 0x3F80, 0x3F80, 0x3F80};

  STAGE_W(0, 0)
  STAGE_W(1, 1)
#pragma unroll 1
  for (int it = 0; it < 14; ++it) {
    WAIT_VM(8)
    COMPUTE_W(it & 1)
    WAIT_LGKM
    STAGE_W(it & 1, it + 2)
  }
  WAIT_VM(8)
  COMPUTE_W(0)
  WAIT_VM(0)
  COMPUTE_W(1)

  // ---- cross-wave reduction: O/l summed over the 4 k-quarters ----
#pragma unroll
  for (int qi = 0; qi < 4; ++qi) {
#pragma unroll
    for (int dd = 0; dd < 2; ++dd)
      *reinterpret_cast<f32x4*>(region + (((qi * 3 + dd) * 64) + lane) * 16) = oacc[qi][dd];
    *reinterpret_cast<f32x4*>(region + (((qi * 3 + 2) * 64) + lane) * 16) = lacc[qi];
  }
  __syncthreads();
  f32x4 osum[2], lsum;
  osum[0] = (f32x4){0.f, 0.f, 0.f, 0.f};
  osum[1] = (f32x4){0.f, 0.f, 0.f, 0.f};
  lsum = (f32x4){0.f, 0.f, 0.f, 0.f};
#pragma unroll
  for (int wp = 0; wp < 4; ++wp) {
    const char* rr = smem + wp * 16384;
    osum[0] += *reinterpret_cast<const f32x4*>(rr + (((w * 3 + 0) * 64) + lane) * 16);
    osum[1] += *reinterpret_cast<const f32x4*>(rr + (((w * 3 + 1) * 64) + lane) * 16);
    lsum += *reinterpret_cast<const f32x4*>(rr + (((w * 3 + 2) * 64) + lane) * 16);
  }
#pragma unroll
  for (int r = 0; r < 4; ++r) {
    float rl = 1.0f / lsum[r];
#pragma unroll
    for (int dd = 0; dd < 2; ++dd)
      aot[(size_t)(nq0 + 16 * w + 4 * lg + r) * C_DIM + hc + 16 * dd + lc] =
          f2bf(osum[dd][r] * rl);
  }
}

// ------ final: out[o][p] = x[o][p] + gamma*(sum_c wo[o][c]*aot[p][c] + bo) --
__global__ __launch_bounds__(256) void gemm_out(const unsigned short* __restrict__ Wb,
                                                const unsigned short* __restrict__ aot,
                                                const float* __restrict__ bias,
                                                const float* __restrict__ x,
                                                const float* __restrict__ gamma,
                                                float* __restrict__ out) {
  int t = threadIdx.x;
  int w = t >> 6, lc = t & 15, lg = (t & 63) >> 4;
  int o_base = blockIdx.y * 64 + (w >> 1) * 32;
  int p_base = blockIdx.x * 64 + (w & 1) * 32;
  f32x4 acc[2][2];
#pragma unroll
  for (int mi = 0; mi < 2; ++mi)
#pragma unroll
    for (int ni = 0; ni < 2; ++ni) acc[mi][ni] = (f32x4){0.f, 0.f, 0.f, 0.f};
#pragma unroll
  for (int c0 = 0; c0 < 256; c0 += 32) {
    bf16x8 a[2], b[2];
#pragma unroll
    for (int mi = 0; mi < 2; ++mi)
      a[mi] = *reinterpret_cast<const bf16x8*>(
          Wb + (size_t)(o_base + 16 * mi + lc) * C_DIM + c0 + 8 * lg);
#pragma unroll
    for (int ni = 0; ni < 2; ++ni)
      b[ni] = *reinterpret_cast<const bf16x8*>(
          aot + (size_t)(p_base + 16 * ni + lc) * C_DIM + c0 + 8 * lg);
#pragma unroll
    for (int mi = 0; mi < 2; ++mi)
#pragma unroll
      for (int ni = 0; ni < 2; ++ni)
        acc[mi][ni] = __builtin_amdgcn_mfma_f32_16x16x32_bf16(a[mi], b[ni], acc[mi][ni], 0, 0, 0);
  }
  float g = gamma[0];
#pragma unroll
  for (int mi = 0; mi < 2; ++mi)
#pragma unroll
    for (int r = 0; r < 4; ++r) {
      int o = o_base + 16 * mi + 4 * lg + r;
      float bvv = bias[o];
#pragma unroll
      for (int ni = 0; ni < 2; ++ni) {
        size_t idx = (size_t)o * N_SP + p_base + 16 * ni + lc;
        out[idx] = x[idx] + g * (acc[mi][ni][r] + bvv);
      }
    }
}

extern "C" void kernel_launch(void* const* d_in, const int* in_sizes, int n_in,
                              void* d_out, int out_size, void* d_ws, size_t ws_size,
                              hipStream_t stream) {
  const float* x   = (const float*)d_in[0];
  const float* wq  = (const float*)d_in[1];
  const float* bq  = (const float*)d_in[2];
  const float* wk  = (const float*)d_in[3];
  const float* bk  = (const float*)d_in[4];
  const float* wv  = (const float*)d_in[5];
  const float* bv  = (const float*)d_in[6];
  const float* wo  = (const float*)d_in[7];
  const float* bo  = (const float*)d_in[8];
  const float* gsc = (const float*)d_in[9];
  const float* gbi = (const float*)d_in[10];
  const float* gamma = (const float*)d_in[11];
  float* out = (float*)d_out;

  char* ws = (char*)d_ws;                                      // ws_size ~256 MiB
  float* pstats         = (float*)(ws + 256);                  // 512 B [8][8][2]
  unsigned short* wbf   = (unsigned short*)(ws + 1024);        // 512 KiB
  unsigned short* qt    = (unsigned short*)(ws + 525312);      // 2 MiB [4096][256]
  unsigned short* kt    = (unsigned short*)(ws + 2622464);     // 2 MiB
  unsigned short* vv    = (unsigned short*)(ws + 4719616);     // 2 MiB [256][4096]
  unsigned short* aot   = (unsigned short*)(ws + 6816768);     // 2 MiB [4096][256]

  stats_cvt<<<128, 1024, 0, stream>>>(x, pstats, wq, wk, wv, wo, wbf);
  gn_qkv<<<512, 256, 0, stream>>>(x, pstats, gsc, gbi, wbf, bq, bk, bv, qt, kt, vv);
  attn_part<<<512, 256, 0, stream>>>(qt, kt, vv, aot);
  gemm_out<<<dim3(64, 4), 256, 0, stream>>>(wbf + 3 * 65536, aot, bo, x, gamma, out);
}

// Round 18
// 61.660 us; speedup vs baseline: 1.0070x; 1.0070x over previous
//
#include <hip/hip_runtime.h>
#include <hip/hip_bf16.h>

#define C_DIM 256
#define N_SP  4096
#define HEADS 8
#define HD    32
#define GSIZE (HD * N_SP)

typedef __attribute__((ext_vector_type(8))) short bf16x8;
typedef __attribute__((ext_vector_type(4))) float f32x4;
typedef __attribute__((ext_vector_type(4))) unsigned u32x4;

__device__ inline unsigned short f2bf(float f) {
  unsigned int u = __builtin_bit_cast(unsigned int, f);
  u = (u + 0x7fffu + ((u >> 16) & 1u)) >> 16;   // RNE
  return (unsigned short)u;
}
__device__ inline float bf2f(unsigned short b) {
  return __builtin_bit_cast(float, (unsigned)b << 16);
}

__device__ inline unsigned cvtpk_bf16(float lo, float hi) {
  unsigned r;
  asm("v_cvt_pk_bf16_f32 %0, %1, %2" : "=v"(r) : "v"(lo), "v"(hi));
  return r;
}
__device__ inline void pl32swap(unsigned &x, unsigned &y) {
  asm("v_permlane32_swap_b32 %0, %1" : "+v"(x), "+v"(y));
}
__device__ inline void pl16swap(unsigned &x, unsigned &y) {
  asm("v_permlane16_swap_b32 %0, %1" : "+v"(x), "+v"(y));
}
__device__ inline void gload_lds16(const void* g, void* l) {
  __builtin_amdgcn_global_load_lds(
      (const __attribute__((address_space(1))) void*)g,
      (__attribute__((address_space(3))) void*)l, 16, 0, 0);
}

// ---- fused: GN partial stats (blocks 0-63, 8 sub/group) + w-cvt (64-127) ---
__global__ __launch_bounds__(1024) void stats_cvt(const float* __restrict__ x,
                                                  float* __restrict__ pstats,
                                                  const float* __restrict__ wq,
                                                  const float* __restrict__ wk,
                                                  const float* __restrict__ wv,
                                                  const float* __restrict__ wo,
                                                  unsigned short* __restrict__ dst) {
  int t = threadIdx.x;
  if (blockIdx.x < 64) {
    int g = blockIdx.x >> 3, sub = blockIdx.x & 7;
    const float4* xg = reinterpret_cast<const float4*>(
        x + (size_t)g * GSIZE + (size_t)sub * (GSIZE / 8));
    float s1 = 0.f, s2 = 0.f;
#pragma unroll
    for (int i = 0; i < 4; ++i) {
      float4 v = xg[t + i * 1024];
      s1 += v.x + v.y + v.z + v.w;
      s2 += v.x * v.x + v.y * v.y + v.z * v.z + v.w * v.w;
    }
    for (int off = 1; off < 64; off <<= 1) {
      s1 += __shfl_xor(s1, off);
      s2 += __shfl_xor(s2, off);
    }
    __shared__ float red[16][2];
    int wid = t >> 6;
    if ((t & 63) == 0) { red[wid][0] = s1; red[wid][1] = s2; }
    __syncthreads();
    if (t < 16) {
      s1 = red[t][0]; s2 = red[t][1];
      for (int off = 1; off < 16; off <<= 1) {
        s1 += __shfl_xor(s1, off);
        s2 += __shfl_xor(s2, off);
      }
      if (t == 0) {
        pstats[(g * 8 + sub) * 2] = s1;
        pstats[(g * 8 + sub) * 2 + 1] = s2;
      }
    }
  } else {
    int i = (blockIdx.x - 64) * 1024 + t;   // 0..65535, quad index
    int mat = i >> 14;
    int idx = i & 16383;
    const float* src = (mat == 0) ? wq : (mat == 1) ? wk : (mat == 2) ? wv : wo;
    float4 v = reinterpret_cast<const float4*>(src)[idx];
    ushort4 o;
    o.x = f2bf(v.x); o.y = f2bf(v.y); o.z = f2bf(v.z); o.w = f2bf(v.w);
    reinterpret_cast<ushort4*>(dst + (size_t)mat * 65536)[idx] = o;
  }
}

// ---- fused GN-apply + QKV projection -----
// 512 blocks x 256 thr: block = 16 p-rows (bid>>1) x 128 o-half (bid&1).
__global__ __launch_bounds__(256) void gn_qkv(const float* __restrict__ x,
                                              const float* __restrict__ pstats,
                                              const float* __restrict__ gsc,
                                              const float* __restrict__ gbi,
                                              const unsigned short* __restrict__ wbf,
                                              const float* __restrict__ bq,
                                              const float* __restrict__ bk,
                                              const float* __restrict__ bv,
                                              unsigned short* __restrict__ qt,
                                              unsigned short* __restrict__ kt,
                                              unsigned short* __restrict__ vv) {
  __shared__ unsigned short xt[16][264];   // 8448 B, row pitch 528 B
  int t = threadIdx.x;
  int p0 = (blockIdx.x >> 1) * 16;
  int oh = (blockIdx.x & 1) * 128;

  // ---- phase 1 ----
  {
    int pl = t & 15;          // p within slab
    int cb = t >> 4;          // 16-channel chunk 0..15
    int c0 = cb * 16;
    int g = c0 >> 5;
    float s1 = 0.f, s2 = 0.f;
#pragma unroll
    for (int s = 0; s < 8; ++s) {
      s1 += pstats[(g * 8 + s) * 2];
      s2 += pstats[(g * 8 + s) * 2 + 1];
    }
    float mu = s1 / (float)GSIZE;
    float rs = rsqrtf(s2 / (float)GSIZE - mu * mu + 1e-5f);
#pragma unroll
    for (int j = 0; j < 16; ++j) {
      float sc = gsc[c0 + j] * rs;
      float bi = gbi[c0 + j] - mu * sc;
      xt[pl][c0 + j] = f2bf(x[(size_t)(c0 + j) * N_SP + p0 + pl] * sc + bi);
    }
  }
  __syncthreads();

  // ---- phase 2 ----
  int w = t >> 6, lc = t & 15, lg = (t & 63) >> 4;
  int ow = oh + w * 32;
  f32x4 aq[2], ak[2], av[2];
#pragma unroll
  for (int i = 0; i < 2; ++i) {
    aq[i] = (f32x4){0.f, 0.f, 0.f, 0.f};
    ak[i] = (f32x4){0.f, 0.f, 0.f, 0.f};
    av[i] = (f32x4){0.f, 0.f, 0.f, 0.f};
  }
#pragma unroll
  for (int it = 0; it < 8; ++it) {
    bf16x8 a = *reinterpret_cast<const bf16x8*>(&xt[lc][it * 32 + 8 * lg]);
#pragma unroll
    for (int ni = 0; ni < 2; ++ni) {
      size_t rowoff = (size_t)(ow + 16 * ni + lc) * C_DIM + it * 32 + 8 * lg;
      bf16x8 bQ = *reinterpret_cast<const bf16x8*>(wbf + rowoff);
      bf16x8 bK = *reinterpret_cast<const bf16x8*>(wbf + 65536 + rowoff);
      bf16x8 bV = *reinterpret_cast<const bf16x8*>(wbf + 131072 + rowoff);
      aq[ni] = __builtin_amdgcn_mfma_f32_16x16x32_bf16(a, bQ, aq[ni], 0, 0, 0);
      ak[ni] = __builtin_amdgcn_mfma_f32_16x16x32_bf16(a, bK, ak[ni], 0, 0, 0);
      av[ni] = __builtin_amdgcn_mfma_f32_16x16x32_bf16(bV, a, av[ni], 0, 0, 0);
    }
  }
#pragma unroll
  for (int ni = 0; ni < 2; ++ni) {
    int o = ow + 16 * ni + lc;
    float bqv = bq[o], bkv = bk[o];
#pragma unroll
    for (int r = 0; r < 4; ++r) {
      qt[(size_t)(p0 + 4 * lg + r) * C_DIM + o] =
          f2bf((aq[ni][r] + bqv) * 0.25503344494963116f);  // hd^-0.5 * log2(e)
      kt[(size_t)(p0 + 4 * lg + r) * C_DIM + o] = f2bf(ak[ni][r] + bkv);
    }
  }
#pragma unroll
  for (int mi = 0; mi < 2; ++mi)
#pragma unroll
    for (int r = 0; r < 4; ++r) {
      int o = ow + 16 * mi + 4 * lg + r;
      vv[(size_t)o * N_SP + p0 + lc] = f2bf(av[mi][r] + bv[o]);
    }
}

// ------------- flash attention (no-max, wave-private ksplit, 0-barrier) ----
// grid (64, 8); block = 4 waves sharing the SAME 64 queries; wave w owns keys
// [w*1024, w*1024+1024) = 16 tiles of 64, staged into its PRIVATE 16 KB LDS
// region (double-buffered 8 KB halves: K 4K + V 4K) via global_load_lds with
// counted vmcnt(8) -- no __syncthreads in the main loop. XOR swizzle formulas
// identical to the R8-verified ones. End: one barrier, cross-wave O/l
// reduction in LDS, normalize, write aot directly (po/lp/merge eliminated).

#define STAGE_W(BUF, IT)                                                      \
  {                                                                           \
    _Pragma("unroll")                                                         \
    for (int i = 0; i < 4; ++i)                                               \
      gload_lds16(ksrc + (size_t)(IT) * 32768 + i * 8192,                     \
                  region + (BUF) * 8192 + i * 1024);                          \
    _Pragma("unroll")                                                         \
    for (int j = 0; j < 4; ++j)                                               \
      gload_lds16(vsrc + (size_t)(IT) * 128 + j * 65536,                      \
                  region + (BUF) * 8192 + 4096 + j * 1024);                   \
  }

#define CHAIN(KF, VF)                                                         \
  {                                                                           \
    f32x4 s[4];                                                               \
    _Pragma("unroll")                                                         \
    for (int ni = 0; ni < 4; ++ni) {                                          \
      f32x4 z = (f32x4){0.f, 0.f, 0.f, 0.f};                                  \
      s[ni] = __builtin_amdgcn_mfma_f32_16x16x32_bf16(KF[ni], qf[qi], z, 0, 0, 0); \
    }                                                                         \
    unsigned wd[4][2];                                                        \
    _Pragma("unroll")                                                         \
    for (int ni = 0; ni < 4; ++ni) {                                          \
      float p0e = __builtin_amdgcn_exp2f(s[ni][0]);                           \
      float p1e = __builtin_amdgcn_exp2f(s[ni][1]);                           \
      float p2e = __builtin_amdgcn_exp2f(s[ni][2]);                           \
      float p3e = __builtin_amdgcn_exp2f(s[ni][3]);                           \
      wd[ni][0] = cvtpk_bf16(p0e, p1e);                                       \
      wd[ni][1] = cvtpk_bf16(p2e, p3e);                                       \
    }                                                                         \
    bf16x8 ap[2];                                                             \
    _Pragma("unroll")                                                         \
    for (int kk = 0; kk < 2; ++kk) {                                          \
      unsigned a0 = wd[2 * kk][0], b0 = wd[2 * kk + 1][0];                    \
      unsigned a1 = wd[2 * kk][1], b1 = wd[2 * kk + 1][1];                    \
      pl32swap(a0, b0); pl16swap(a0, b0);                                     \
      pl32swap(a1, b1); pl16swap(a1, b1);                                     \
      u32x4 pk = {a0, a1, b0, b1};                                            \
      ap[kk] = __builtin_bit_cast(bf16x8, pk);                                \
    }                                                                         \
    lacc[qi] = __builtin_amdgcn_mfma_f32_16x16x32_bf16(ap[0], ones, lacc[qi], 0, 0, 0); \
    oacc[qi][0] = __builtin_amdgcn_mfma_f32_16x16x32_bf16(ap[0], VF[0][0], oacc[qi][0], 0, 0, 0); \
    oacc[qi][1] = __builtin_amdgcn_mfma_f32_16x16x32_bf16(ap[0], VF[0][1], oacc[qi][1], 0, 0, 0); \
    lacc[qi] = __builtin_amdgcn_mfma_f32_16x16x32_bf16(ap[1], ones, lacc[qi], 0, 0, 0); \
    oacc[qi][0] = __builtin_amdgcn_mfma_f32_16x16x32_bf16(ap[1], VF[1][0], oacc[qi][0], 0, 0, 0); \
    oacc[qi][1] = __builtin_amdgcn_mfma_f32_16x16x32_bf16(ap[1], VF[1][1], oacc[qi][1], 0, 0, 0); \
  }

#define COMPUTE_W(BUF)                                                        \
  {                                                                           \
    bf16x8 kf[4], vf[2][2];                                                   \
    _Pragma("unroll")                                                         \
    for (int ni = 0; ni < 4; ++ni)                                            \
      kf[ni] = *reinterpret_cast<const bf16x8*>(region + (BUF) * 8192 + ni * 1024 + krd); \
    _Pragma("unroll")                                                         \
    for (int dd = 0; dd < 2; ++dd) {                                          \
      vf[0][dd] = *reinterpret_cast<const bf16x8*>(region + (BUF) * 8192 + 4096 + dd * 2048 + vrd0); \
      vf[1][dd] = *reinterpret_cast<const bf16x8*>(region + (BUF) * 8192 + 4096 + dd * 2048 + vrd1); \
    }                                                                         \
    _Pragma("unroll")                                                         \
    for (int qi = 0; qi < 4; ++qi) { CHAIN(kf, vf) }                          \
  }

#define WAIT_VM(N)                                                            \
  {                                                                           \
    asm volatile("s_waitcnt vmcnt(" #N ")" ::: "memory");                     \
    __builtin_amdgcn_sched_barrier(0);                                        \
  }
#define WAIT_LGKM                                                             \
  {                                                                           \
    asm volatile("s_waitcnt lgkmcnt(0)" ::: "memory");                        \
    __builtin_amdgcn_sched_barrier(0);                                        \
  }

__global__ __launch_bounds__(256, 2) void attn_part(const unsigned short* __restrict__ qt,
                                                    const unsigned short* __restrict__ kt,
                                                    const unsigned short* __restrict__ v,
                                                    unsigned short* __restrict__ aot) {
  __shared__ __align__(1024) char smem[65536];
  int t = threadIdx.x;
  int w = t >> 6, lane = t & 63, lc = t & 15, lg = (t & 63) >> 4;
  int h = blockIdx.y;
  int hc = h * HD;
  int nq0 = blockIdx.x * 64;
  char* region = smem + w * 16384;

  // per-wave staging sources (inverse-swizzled), quarter = keys [w*1024, +1024)
  int krow = lane >> 2;
  int kc16 = (lane & 3) ^ (krow & 3);
  const char* ksrc = (const char*)(kt + (size_t)(w * 1024 + krow) * C_DIM + hc + 8 * kc16);
  int vrow = lane >> 3;
  int vn16 = (lane & 7) ^ (vrow & 7);
  const char* vsrc = (const char*)(v + (size_t)(hc + vrow) * N_SP + w * 1024 + 8 * vn16);

  // LDS read per-lane byte offsets (swizzled), as R8
  int krd = lc * 64 + 16 * (lg ^ (lc & 3));
  int vrd0 = lc * 128 + 16 * ((lg + 0) ^ (lc & 7));
  int vrd1 = lc * 128 + 16 * ((lg + 4) ^ (lc & 7));

  bf16x8 qf[4];
#pragma unroll
  for (int qi = 0; qi < 4; ++qi)
    qf[qi] = *reinterpret_cast<const bf16x8*>(
        qt + (size_t)(nq0 + 16 * qi + lc) * C_DIM + hc + 8 * lg);

  f32x4 oacc[4][2], lacc[4];
#pragma unroll
  for (int qi = 0; qi < 4; ++qi) {
    lacc[qi] = (f32x4){0.f, 0.f, 0.f, 0.f};
#pragma unroll
    for (int dd = 0; dd < 2; ++dd) oacc[qi][dd] = (f32x4){0.f, 0.f, 0.f, 0.f};
  }
  const bf16x8 ones = {0x3F80, 0x3F80, 0x3F80, 0x3F80, 0x3F80, 0x3F80, 0x3F80, 0x3F80};

  STAGE_W(0, 0)
  STAGE_W(1, 1)
#pragma unroll 1
  for (int it = 0; it < 14; ++it) {
    WAIT_VM(8)
    COMPUTE_W(it & 1)
    WAIT_LGKM
    STAGE_W(it & 1, it + 2)
  }
  WAIT_VM(8)
  COMPUTE_W(0)
  WAIT_VM(0)
  COMPUTE_W(1)

  // ---- cross-wave reduction: O/l summed over the 4 k-quarters ----
  // layout per wave region: [(qi*3+slot)*64 + lane] f32x4 (slot 0,1=dd, 2=l)
#pragma unroll
  for (int qi = 0; qi < 4; ++qi) {
#pragma unroll
    for (int dd = 0; dd < 2; ++dd)
      *reinterpret_cast<f32x4*>(region + (((qi * 3 + dd) * 64) + lane) * 16) = oacc[qi][dd];
    *reinterpret_cast<f32x4*>(region + (((qi * 3 + 2) * 64) + lane) * 16) = lacc[qi];
  }
  __syncthreads();
  f32x4 osum[2], lsum;
  osum[0] = (f32x4){0.f, 0.f, 0.f, 0.f};
  osum[1] = (f32x4){0.f, 0.f, 0.f, 0.f};
  lsum = (f32x4){0.f, 0.f, 0.f, 0.f};
#pragma unroll
  for (int wp = 0; wp < 4; ++wp) {
    const char* rr = smem + wp * 16384;
    osum[0] += *reinterpret_cast<const f32x4*>(rr + (((w * 3 + 0) * 64) + lane) * 16);
    osum[1] += *reinterpret_cast<const f32x4*>(rr + (((w * 3 + 1) * 64) + lane) * 16);
    lsum += *reinterpret_cast<const f32x4*>(rr + (((w * 3 + 2) * 64) + lane) * 16);
  }
#pragma unroll
  for (int r = 0; r < 4; ++r) {
    float rl = 1.0f / lsum[r];
#pragma unroll
    for (int dd = 0; dd < 2; ++dd)
      aot[(size_t)(nq0 + 16 * w + 4 * lg + r) * C_DIM + hc + 16 * dd + lc] =
          f2bf(osum[dd][r] * rl);
  }
}

// ------ final: out[o][p] = x[o][p] + gamma*(sum_c wo[o][c]*aot[p][c] + bo) --
__global__ __launch_bounds__(256) void gemm_out(const unsigned short* __restrict__ Wb,
                                                const unsigned short* __restrict__ aot,
                                                const float* __restrict__ bias,
                                                const float* __restrict__ x,
                                                const float* __restrict__ gamma,
                                                float* __restrict__ out) {
  int t = threadIdx.x;
  int w = t >> 6, lc = t & 15, lg = (t & 63) >> 4;
  int o_base = blockIdx.y * 64 + (w >> 1) * 32;
  int p_base = blockIdx.x * 64 + (w & 1) * 32;
  f32x4 acc[2][2];
#pragma unroll
  for (int mi = 0; mi < 2; ++mi)
#pragma unroll
    for (int ni = 0; ni < 2; ++ni) acc[mi][ni] = (f32x4){0.f, 0.f, 0.f, 0.f};
#pragma unroll
  for (int c0 = 0; c0 < 256; c0 += 32) {
    bf16x8 a[2], b[2];
#pragma unroll
    for (int mi = 0; mi < 2; ++mi)
      a[mi] = *reinterpret_cast<const bf16x8*>(
          Wb + (size_t)(o_base + 16 * mi + lc) * C_DIM + c0 + 8 * lg);
#pragma unroll
    for (int ni = 0; ni < 2; ++ni)
      b[ni] = *reinterpret_cast<const bf16x8*>(
          aot + (size_t)(p_base + 16 * ni + lc) * C_DIM + c0 + 8 * lg);
#pragma unroll
    for (int mi = 0; mi < 2; ++mi)
#pragma unroll
      for (int ni = 0; ni < 2; ++ni)
        acc[mi][ni] = __builtin_amdgcn_mfma_f32_16x16x32_bf16(a[mi], b[ni], acc[mi][ni], 0, 0, 0);
  }
  float g = gamma[0];
#pragma unroll
  for (int mi = 0; mi < 2; ++mi)
#pragma unroll
    for (int r = 0; r < 4; ++r) {
      int o = o_base + 16 * mi + 4 * lg + r;
      float bvv = bias[o];
#pragma unroll
      for (int ni = 0; ni < 2; ++ni) {
        size_t idx = (size_t)o * N_SP + p_base + 16 * ni + lc;
        out[idx] = x[idx] + g * (acc[mi][ni][r] + bvv);
      }
    }
}

extern "C" void kernel_launch(void* const* d_in, const int* in_sizes, int n_in,
                              void* d_out, int out_size, void* d_ws, size_t ws_size,
                              hipStream_t stream) {
  const float* x   = (const float*)d_in[0];
  const float* wq  = (const float*)d_in[1];
  const float* bq  = (const float*)d_in[2];
  const float* wk  = (const float*)d_in[3];
  const float* bk  = (const float*)d_in[4];
  const float* wv  = (const float*)d_in[5];
  const float* bv  = (const float*)d_in[6];
  const float* wo  = (const float*)d_in[7];
  const float* bo  = (const float*)d_in[8];
  const float* gsc = (const float*)d_in[9];
  const float* gbi = (const float*)d_in[10];
  const float* gamma = (const float*)d_in[11];
  float* out = (float*)d_out;

  char* ws = (char*)d_ws;                                      // ws_size ~256 MiB
  float* pstats         = (float*)(ws + 256);                  // 512 B [8][8][2]
  unsigned short* wbf   = (unsigned short*)(ws + 1024);        // 512 KiB
  unsigned short* qt    = (unsigned short*)(ws + 525312);      // 2 MiB [4096][256]
  unsigned short* kt    = (unsigned short*)(ws + 2622464);     // 2 MiB
  unsigned short* vv    = (unsigned short*)(ws + 4719616);     // 2 MiB [256][4096]
  unsigned short* aot   = (unsigned short*)(ws + 6816768);     // 2 MiB [4096][256]

  stats_cvt<<<128, 1024, 0, stream>>>(x, pstats, wq, wk, wv, wo, wbf);
  gn_qkv<<<512, 256, 0, stream>>>(x, pstats, gsc, gbi, wbf, bq, bk, bv, qt, kt, vv);
  attn_part<<<dim3(64, 8), 256, 0, stream>>>(qt, kt, vv, aot);
  gemm_out<<<dim3(64, 4), 256, 0, stream>>>(wbf + 3 * 65536, aot, bo, x, gamma, out);
}